// Round 7
// baseline (4296.454 us; speedup 1.0000x reference)
//
#include <hip/hip_runtime.h>

#define LSEQ 512
#define BATCH 256
#define KDIM 256
#define STATE 128

using f32x4  = __attribute__((ext_vector_type(4))) float;
using short8 = __attribute__((ext_vector_type(8))) short;
using u32x4  = __attribute__((ext_vector_type(4))) unsigned int;

__device__ __forceinline__ float bf2f(unsigned short u){
  return __uint_as_float(((unsigned int)u) << 16);
}
__device__ __forceinline__ unsigned short f2bf(float f){
  unsigned int u = __float_as_uint(f);
  u += 0x7FFFu + ((u >> 16) & 1u);   // RNE
  return (unsigned short)(u >> 16);
}
__device__ __forceinline__ float lo16f(unsigned u){ return __uint_as_float(u << 16); }
__device__ __forceinline__ float hi16f(unsigned u){ return __uint_as_float(u & 0xFFFF0000u); }
__device__ __forceinline__ float fast_tanh(float x){
  float ax = fabsf(x);
  float e  = __expf(2.0f * ax);
  float t  = 1.0f - 2.0f / (e + 1.0f);
  return copysignf(t, x);
}
__device__ __forceinline__ float fast_sig(float x){
  return 1.0f / (1.0f + __expf(-x));
}
__device__ __forceinline__ f32x4 mfma16(short8 a, short8 b, f32x4 c){
  return __builtin_amdgcn_mfma_f32_16x16x32_bf16(a, b, c, 0, 0, 0);
}

__device__ __forceinline__ int swz128 (int b){ return b ^ ((((b >> 7) & 7) << 4)); }
__device__ __forceinline__ int swz256 (int b){ return b ^ ((((b >> 8) & 7) << 4)); }
__device__ __forceinline__ int swz512 (int b){ return b ^ ((((b >> 9) & 7) << 4)); }

// ---- Infinity-Cache-scope accessors (sc0 sc1): coherent on any XCD placement,
// no cache-maintenance ops. Protocol: self-validating 16B lines
// [6 bf16 | 4B tag], single-instruction store => observed atomically.
__device__ __forceinline__ void st_b128_ic(void* p, u32x4 v){
  asm volatile("global_store_dwordx4 %0, %1, off sc0 sc1" :: "v"(p), "v"(v) : "memory");
}
#define LD4_IC(dst, p) asm volatile("global_load_dwordx4 %0, %1, off sc0 sc1" : "=v"(dst) : "v"(p) : "memory")

// ---------------- weight convert: f32 src[rowoff+k][coloff+n] -> bf16 dst[n*K+k] ----------------
struct WDesc { const float* src; unsigned short* dst; int K, N, ld, rowoff, coloff; };
struct WDescs { WDesc d[24]; };

__global__ __launch_bounds__(256,4) void convert_weights(WDescs ds){
  WDesc w = ds.d[blockIdx.y];
  int total = w.K * w.N;
  int idx = blockIdx.x * 256 + threadIdx.x;
  if (idx < total){
    int n = idx / w.K;
    int k = idx - n * w.K;
    w.dst[idx] = f2bf(w.src[(size_t)(w.rowoff + k) * w.ld + w.coloff + n]);
  }
}

// ---------------- multi-descriptor bf16 MFMA GEMM ----------------
struct GArg {
  const void* A; const unsigned short* Bt; const float* bias; const float* bias2;
  unsigned short* C; int lda, ldc, coff, K, act, a_f32;
};
struct GArgs { GArg g[4]; };

__global__ __launch_bounds__(256,2) void gemm_multi(GArgs args){
  GArg ga = args.g[blockIdx.z];
  __shared__ __align__(16) unsigned short lsA[128*64];
  __shared__ __align__(16) unsigned short lsB[128*64];
  const int tid  = threadIdx.x;
  const int wave = tid >> 6, lane = tid & 63;
  const int col_l = lane & 15, rgrp = lane >> 4;
  const int m0 = blockIdx.x * 128, n0 = blockIdx.y * 128;
  const int wm = (wave >> 1) * 64, wn = (wave & 1) * 64;

  f32x4 acc[4][4];
  const f32x4 z4 = {0.f,0.f,0.f,0.f};
  #pragma unroll
  for (int i=0;i<4;i++){ acc[i][0]=z4; acc[i][1]=z4; acc[i][2]=z4; acc[i][3]=z4; }

  const int srow = tid >> 1;
  const int sbe  = (tid & 1) * 32;

  for (int k0 = 0; k0 < ga.K; k0 += 64){
    uint4 av[4], bv[4];
    if (ga.a_f32){
      const float* Ap = (const float*)ga.A + (size_t)(m0 + srow) * ga.lda + k0 + sbe;
      uint4 fv[8];
      #pragma unroll
      for (int i=0;i<8;i++) fv[i] = *(const uint4*)((const char*)Ap + i*16);
      #pragma unroll
      for (int i=0;i<4;i++){
        const float* f = (const float*)&fv[i*2];
        uint4 o;
        o.x = (unsigned)f2bf(f[0]) | ((unsigned)f2bf(f[1]) << 16);
        o.y = (unsigned)f2bf(f[2]) | ((unsigned)f2bf(f[3]) << 16);
        o.z = (unsigned)f2bf(f[4]) | ((unsigned)f2bf(f[5]) << 16);
        o.w = (unsigned)f2bf(f[6]) | ((unsigned)f2bf(f[7]) << 16);
        av[i] = o;
      }
    } else {
      const unsigned short* Ap = (const unsigned short*)ga.A + (size_t)(m0 + srow) * ga.lda + k0 + sbe;
      #pragma unroll
      for (int i=0;i<4;i++) av[i] = *(const uint4*)((const char*)Ap + i*16);
    }
    const unsigned short* Bp = ga.Bt + (size_t)(n0 + srow) * ga.K + k0 + sbe;
    #pragma unroll
    for (int i=0;i<4;i++) bv[i] = *(const uint4*)((const char*)Bp + i*16);

    __syncthreads();
    #pragma unroll
    for (int i=0;i<4;i++){
      *(uint4*)((char*)lsA + swz128(srow*128 + sbe*2 + i*16)) = av[i];
      *(uint4*)((char*)lsB + swz128(srow*128 + sbe*2 + i*16)) = bv[i];
    }
    __syncthreads();
    #pragma unroll
    for (int kk=0; kk<2; kk++){
      short8 af[4], bfr[4];
      #pragma unroll
      for (int mt=0; mt<4; mt++)
        af[mt] = *(const short8*)((const char*)lsA + swz128((wm + mt*16 + col_l)*128 + kk*64 + rgrp*16));
      #pragma unroll
      for (int nt=0; nt<4; nt++)
        bfr[nt] = *(const short8*)((const char*)lsB + swz128((wn + nt*16 + col_l)*128 + kk*64 + rgrp*16));
      #pragma unroll
      for (int mt=0; mt<4; mt++)
        #pragma unroll
        for (int nt=0; nt<4; nt++)
          acc[mt][nt] = mfma16(af[mt], bfr[nt], acc[mt][nt]);
    }
  }
  #pragma unroll
  for (int nt=0; nt<4; nt++){
    int col = n0 + wn + nt*16 + col_l;
    const float* bsrc = (col < 512) ? ga.bias : ga.bias2;
    float bb = bsrc ? bsrc[col & 511] : 0.0f;
    #pragma unroll
    for (int mt=0; mt<4; mt++){
      #pragma unroll
      for (int r=0; r<4; r++){
        int row = m0 + wm + mt*16 + rgrp*4 + r;
        float v = acc[mt][nt][r] + bb;
        if (ga.act == 1) v = fast_tanh(v);
        ga.C[(size_t)row * ga.ldc + ga.coff + col] = f2bf(v);
      }
    }
  }
}

// ---------------- phase B: tanh-RNN chunk, W_hh held in VGPRs ----------------
__global__ __launch_bounds__(256,1) void rnn_chunk(
    const unsigned short* __restrict__ rnn_in,
    const unsigned short* __restrict__ Whh_t,
    const float* __restrict__ b_hh,
    unsigned short* __restrict__ cat_d,
    float* __restrict__ dn_out,
    unsigned short* __restrict__ d_state,
    int t0, int nsteps)
{
  __shared__ __align__(16) unsigned short dls[16*256];
  const int tid = threadIdx.x, wave = tid >> 6, lane = tid & 63;
  const int col_l = lane & 15, rgrp = lane >> 4;
  const int brow0 = blockIdx.x * 16;
  const int ncol = wave * 64;

  short8 bfr[4][8];
  #pragma unroll
  for (int nt=0; nt<4; nt++){
    const unsigned short* bp = Whh_t + (size_t)(ncol + nt*16 + col_l) * 256;
    #pragma unroll
    for (int kk=0; kk<8; kk++)
      bfr[nt][kk] = *(const short8*)(bp + kk*32 + rgrp*8);
  }
  float bias[4];
  #pragma unroll
  for (int nt=0; nt<4; nt++) bias[nt] = b_hh[ncol + nt*16 + col_l];

  if (t0 == 0){
    for (int i = tid; i < 16*256; i += 256){
      int row = i >> 8, col = i & 255;
      *(unsigned short*)((char*)dls + swz512(row*512 + col*2)) = 0;
    }
  } else {
    const unsigned short* ds = d_state + (size_t)brow0 * 256;
    for (int i = tid; i < 16*256; i += 256){
      int row = i >> 8, col = i & 255;
      *(unsigned short*)((char*)dls + swz512(row*512 + col*2)) = ds[row*256 + col];
    }
  }
  __syncthreads();

  for (int tl=0; tl<nsteps; tl++){
    unsigned short rv[4][4];
    const unsigned short* rp = rnn_in + (size_t)(tl*BATCH + brow0) * 256;
    #pragma unroll
    for (int nt=0; nt<4; nt++)
      #pragma unroll
      for (int r=0; r<4; r++)
        rv[nt][r] = rp[(size_t)(rgrp*4 + r)*256 + ncol + nt*16 + col_l];

    f32x4 acc[4];
    const f32x4 z4 = {0.f,0.f,0.f,0.f};
    acc[0]=z4; acc[1]=z4; acc[2]=z4; acc[3]=z4;
    #pragma unroll
    for (int kk=0; kk<8; kk++){
      short8 af = *(const short8*)((const char*)dls + swz512((lane & 15)*512 + kk*64 + rgrp*16));
      #pragma unroll
      for (int nt=0; nt<4; nt++)
        acc[nt] = mfma16(af, bfr[nt][kk], acc[nt]);
    }
    __syncthreads();
    #pragma unroll
    for (int nt=0; nt<4; nt++){
      #pragma unroll
      for (int r=0; r<4; r++){
        float h = acc[nt][r] + bf2f(rv[nt][r]) + bias[nt];
        float d = fast_tanh(h);
        int row = rgrp*4 + r, col = ncol + nt*16 + col_l;
        unsigned short db = f2bf(d);
        *(unsigned short*)((char*)dls + swz512(row*512 + col*2)) = db;
        cat_d[(size_t)(tl*BATCH + brow0 + row)*512 + col] = db;
        if (t0 + tl == LSEQ-1) dn_out[(size_t)(brow0 + row)*256 + col] = d;
      }
    }
    __syncthreads();
  }
  unsigned short* dso = d_state + (size_t)brow0 * 256;
  for (int i = tid; i < 16*256; i += 256){
    int row = i >> 8, col = i & 255;
    dso[row*256 + col] = *(const unsigned short*)((const char*)dls + swz512(row*512 + col*2));
  }
}

// ---------------- phase D: weight-stationary z recurrence, tagged-line IC mailbox ----------------
// 16 groups x 16 batch rows x 4 roles; 512 threads (8 waves).
// Lines: 16B = [6 bf16 data | 4B tag]; single x4 store (atomic observation).
// Readers poll their own peer lines directly -> ONE IC round trip per step.
// Tags monotone (fbase+tl+1); stale tag matches across graph replays are benign
// (deterministic replay => identical data).
__global__ __launch_bounds__(512,1) void zrec_mb(
    const unsigned short* __restrict__ preP, const unsigned short* __restrict__ preQ, // [ns*B,1024]
    const unsigned short* __restrict__ Wzz,  // [4 roles][2 mats][256 n][128 k]
    const unsigned short* __restrict__ W2,   // [4 roles][2 mats][128 n][256 k]
    const float* __restrict__ pmub, const float* __restrict__ plsb, const float* __restrict__ qmub,
    const float* __restrict__ eps,
    float* __restrict__ out_mu, float* __restrict__ out_ls, float* __restrict__ out_zn,
    unsigned short* __restrict__ z_state,
    unsigned short* __restrict__ mb,
    int t0, int nsteps, int fbase)
{
  __shared__ __align__(16) unsigned short zls[16*128];  // z, stride 256B, swz256
  __shared__ __align__(16) unsigned short tls[16*256];  // t, stride 512B, swz512
  __shared__ __align__(16) unsigned short bls[16*256];  // bounce, LINEAR
  const int tid = threadIdx.x, wave = tid >> 6, lane = tid & 63;
  const int col_l = lane & 15, rgrp = lane >> 4;
  const int bid = blockIdx.x;
  const int c   = (bid >> 3) & 3;                 // role
  const int g   = (bid & 7) + ((bid >> 5) << 3);  // group
  const int brow0 = g * 16;
  const int NT2 = (c < 2) ? 2 : 1;

  const unsigned short* pre = (c < 2) ? preP : preQ;
  const int cb = (c & 1) * 256;

  // GEMM1 weights -> registers
  short8 w1[2][2][4];
  {
    const unsigned short* wz = Wzz + (size_t)c * 65536;
    #pragma unroll
    for (int m=0; m<2; m++)
      #pragma unroll
      for (int nt=0; nt<2; nt++){
        int n = wave*32 + nt*16 + col_l;
        #pragma unroll
        for (int kk=0; kk<4; kk++)
          w1[m][nt][kk] = *(const short8*)(wz + (size_t)(m*256 + n)*128 + kk*32 + rgrp*8);
      }
  }
  // GEMM2 weights -> registers
  short8 w2r[2][8];
  {
    const unsigned short* wp = W2 + (size_t)c * 65536;
    #pragma unroll
    for (int nt=0; nt<2; nt++){
      if (nt < NT2){
        int ccol = wave*(16*((c<2)?2:1)) + nt*16;
        int mat = (c < 2) ? (ccol >> 7) : 0;
        int n   = (ccol & 127) + col_l;
        #pragma unroll
        for (int kk=0; kk<8; kk++)
          w2r[nt][kk] = *(const short8*)(wp + (size_t)(mat*128 + n)*256 + kk*32 + rgrp*8);
      }
    }
  }

  // init z
  if (t0 == 0){
    for (int i = tid; i < 16*128; i += 512){
      int row = i >> 7, col = i & 127;
      *(unsigned short*)((char*)zls + swz256(row*256 + col*2)) = 0;
    }
  } else {
    const unsigned short* zs = z_state + (size_t)brow0 * 128;
    for (int i = tid; i < 16*128; i += 512){
      int row = i >> 7, col = i & 127;
      *(unsigned short*)((char*)zls + swz256(row*256 + col*2)) = zs[row*128 + col];
    }
  }
  __syncthreads();

  auto LD_PRE = [&](int tl, unsigned short (&pa_)[2][4], unsigned short (&pb_)[2][4]){
    const unsigned short* bA = pre + ((size_t)tl*BATCH + brow0)*1024 + cb;
    #pragma unroll
    for (int nt=0; nt<2; nt++)
      #pragma unroll
      for (int r=0; r<4; r++){
        int row = rgrp*4 + r, col = wave*32 + nt*16 + col_l;
        pa_[nt][r] = bA[(size_t)row*1024 + col];
        pb_[nt][r] = bA[(size_t)row*1024 + 512 + col];
      }
  };

  // reduce-phase mapping: thread -> (row, 4 consecutive z-cols)
  const int rrow = tid >> 5;
  const int rc0  = (tid & 31) * 4;
  const f32x4 bp4 = *(const f32x4*)(pmub + rc0);
  const f32x4 bl4 = *(const f32x4*)(plsb + rc0);
  const f32x4 bq4 = *(const f32x4*)(qmub + rc0);

  unsigned short pa0[2][4], pb0[2][4], pa1[2][4], pb1[2][4];
  LD_PRE(0, pa0, pb0);

  const f32x4 z4 = {0.f,0.f,0.f,0.f};
  for (int tl=0; tl<nsteps; ++tl){
    size_t growr = (size_t)(t0+tl)*BATCH + brow0 + rrow;
    f32x4 er = *(const f32x4*)(eps + growr*STATE + rc0);
    int nx = (tl+1 < nsteps) ? tl+1 : tl;
    LD_PRE(nx, pa1, pb1);

    // GEMM1: z @ Wf (both mats), K=128
    short8 af1[4];
    #pragma unroll
    for (int kk=0; kk<4; kk++)
      af1[kk] = *(const short8*)((const char*)zls + swz256((lane & 15)*256 + kk*64 + rgrp*16));
    f32x4 a1[2][2];
    a1[0][0]=z4; a1[0][1]=z4; a1[1][0]=z4; a1[1][1]=z4;
    #pragma unroll
    for (int kk=0; kk<4; kk++)
      #pragma unroll
      for (int m=0; m<2; m++)
        #pragma unroll
        for (int nt=0; nt<2; nt++)
          a1[m][nt] = mfma16(af1[kk], w1[m][nt][kk], a1[m][nt]);

    #pragma unroll
    for (int nt=0; nt<2; nt++)
      #pragma unroll
      for (int r=0; r<4; r++){
        float h1 = a1[0][nt][r] + bf2f(pa0[nt][r]);
        float h2 = a1[1][nt][r] + bf2f(pb0[nt][r]);
        float tv = fast_tanh(h1) * fast_sig(h2);
        int row = rgrp*4 + r, tcol = wave*32 + nt*16 + col_l;
        *(unsigned short*)((char*)tls + swz512(row*512 + tcol*2)) = f2bf(tv);
      }
    __syncthreads();                                   // (1) t visible

    // GEMM2: t @ Wh (local k-slice), K=256
    f32x4 a2[2];
    a2[0]=z4; a2[1]=z4;
    #pragma unroll
    for (int kk=0; kk<8; kk++){
      short8 af2 = *(const short8*)((const char*)tls + swz512((lane & 15)*512 + kk*64 + rgrp*16));
      #pragma unroll
      for (int nt=0; nt<2; nt++)
        if (nt < NT2) a2[nt] = mfma16(af2, w2r[nt][kk], a2[nt]);
    }
    // bounce to LDS (linear layout)
    if (c < 2){
      #pragma unroll
      for (int nt=0; nt<2; nt++)
        #pragma unroll
        for (int r=0; r<4; r++)
          bls[(rgrp*4 + r)*256 + wave*32 + nt*16 + col_l] = f2bf(a2[nt][r]);
    } else {
      #pragma unroll
      for (int r=0; r<4; r++)
        bls[(rgrp*4 + r)*128 + wave*16 + col_l] = f2bf(a2[0][r]);
    }
    __syncthreads();                                   // (2) bounce visible

    // pack + publish tagged lines (fire-and-forget)
    const int target = fbase + tl + 1;
    unsigned short* slot = mb + (size_t)((g*2 + (tl & 1))*4 + c)*8192;
    if (c < 2){
      uint2 muw = *(const uint2*)&bls[rrow*256 + rc0];
      unsigned lsw0 = *(const unsigned*)&bls[rrow*256 + 128 + rc0];
      unsigned lsw1 = *(const unsigned*)&bls[rrow*256 + 128 + rc0 + 2];
      u32x4 lA; lA[0]=muw.x; lA[1]=muw.y; lA[2]=lsw0; lA[3]=(unsigned)target;
      u32x4 lB; lB[0]=lsw1; lB[1]=0; lB[2]=0; lB[3]=(unsigned)target;
      st_b128_ic((char*)slot + tid*32,      lA);
      st_b128_ic((char*)slot + tid*32 + 16, lB);
    } else {
      uint2 qw = *(const uint2*)&bls[rrow*128 + rc0];
      u32x4 lC; lC[0]=qw.x; lC[1]=qw.y; lC[2]=0; lC[3]=(unsigned)target;
      st_b128_ic((char*)slot + tid*16, lC);
    }

    // poll peer lines directly (per-thread; own role from LDS)
    const unsigned short* mbB = mb + (size_t)((g*2 + (tl & 1))*4)*8192;
    f32x4 p0mu, p0ls, p1mu, p1ls, q2v, q3v;
    if (c < 2){
      const char* pa = (const char*)(mbB + (size_t)(c^1)*8192) + tid*32;
      const char* p2 = (const char*)(mbB + (size_t)2*8192) + tid*16;
      const char* p3 = (const char*)(mbB + (size_t)3*8192) + tid*16;
      u32x4 LA, LB, L2, L3;
      for (;;){
        LD4_IC(LA, pa); LD4_IC(LB, pa+16); LD4_IC(L2, p2); LD4_IC(L3, p3);
        asm volatile("s_waitcnt vmcnt(0)" ::: "memory");
        if ((int)LA[3]==target && (int)LB[3]==target && (int)L2[3]==target && (int)L3[3]==target) break;
      }
      f32x4 omu, ols, pmu_, pls_;
      omu[0]=bf2f(bls[rrow*256+rc0+0]); omu[1]=bf2f(bls[rrow*256+rc0+1]);
      omu[2]=bf2f(bls[rrow*256+rc0+2]); omu[3]=bf2f(bls[rrow*256+rc0+3]);
      ols[0]=bf2f(bls[rrow*256+128+rc0+0]); ols[1]=bf2f(bls[rrow*256+128+rc0+1]);
      ols[2]=bf2f(bls[rrow*256+128+rc0+2]); ols[3]=bf2f(bls[rrow*256+128+rc0+3]);
      pmu_[0]=lo16f(LA[0]); pmu_[1]=hi16f(LA[0]); pmu_[2]=lo16f(LA[1]); pmu_[3]=hi16f(LA[1]);
      pls_[0]=lo16f(LA[2]); pls_[1]=hi16f(LA[2]); pls_[2]=lo16f(LB[0]); pls_[3]=hi16f(LB[0]);
      q2v[0]=lo16f(L2[0]); q2v[1]=hi16f(L2[0]); q2v[2]=lo16f(L2[1]); q2v[3]=hi16f(L2[1]);
      q3v[0]=lo16f(L3[0]); q3v[1]=hi16f(L3[0]); q3v[2]=lo16f(L3[1]); q3v[3]=hi16f(L3[1]);
      if (c == 0){ p0mu=omu; p0ls=ols; p1mu=pmu_; p1ls=pls_; }
      else       { p1mu=omu; p1ls=ols; p0mu=pmu_; p0ls=pls_; }
    } else {
      const char* p0 = (const char*)(mbB) + tid*32;
      const char* p1 = (const char*)(mbB + (size_t)8192) + tid*32;
      const char* pq = (const char*)(mbB + (size_t)((c==2)?3:2)*8192) + tid*16;
      u32x4 A0, A1, B0, B1, Q;
      for (;;){
        LD4_IC(A0, p0); LD4_IC(A1, p0+16); LD4_IC(B0, p1); LD4_IC(B1, p1+16); LD4_IC(Q, pq);
        asm volatile("s_waitcnt vmcnt(0)" ::: "memory");
        if ((int)A0[3]==target && (int)A1[3]==target && (int)B0[3]==target &&
            (int)B1[3]==target && (int)Q[3]==target) break;
      }
      p0mu[0]=lo16f(A0[0]); p0mu[1]=hi16f(A0[0]); p0mu[2]=lo16f(A0[1]); p0mu[3]=hi16f(A0[1]);
      p0ls[0]=lo16f(A0[2]); p0ls[1]=hi16f(A0[2]); p0ls[2]=lo16f(A1[0]); p0ls[3]=hi16f(A1[0]);
      p1mu[0]=lo16f(B0[0]); p1mu[1]=hi16f(B0[0]); p1mu[2]=lo16f(B0[1]); p1mu[3]=hi16f(B0[1]);
      p1ls[0]=lo16f(B0[2]); p1ls[1]=hi16f(B0[2]); p1ls[2]=lo16f(B1[0]); p1ls[3]=hi16f(B1[0]);
      f32x4 oq, pq_;
      oq[0]=bf2f(bls[rrow*128+rc0+0]); oq[1]=bf2f(bls[rrow*128+rc0+1]);
      oq[2]=bf2f(bls[rrow*128+rc0+2]); oq[3]=bf2f(bls[rrow*128+rc0+3]);
      pq_[0]=lo16f(Q[0]); pq_[1]=hi16f(Q[0]); pq_[2]=lo16f(Q[1]); pq_[3]=hi16f(Q[1]);
      if (c == 2){ q2v=oq; q3v=pq_; } else { q3v=oq; q2v=pq_; }
    }

    // reduce (identical fp order on all roles)
    f32x4 mup = p0mu + p1mu;
    f32x4 lsv = p0ls + p1ls + bl4;
    f32x4 muq = q2v + q3v;
    f32x4 muv = (muq + bq4) + (mup + bp4);
    f32x4 zv;
    #pragma unroll
    for (int i=0; i<4; i++) zv[i] = muv[i] + __expf(0.5f * lsv[i]) * er[i];

    unsigned int lo = (unsigned)f2bf(zv[0]) | ((unsigned)f2bf(zv[1]) << 16);
    unsigned int hi = (unsigned)f2bf(zv[2]) | ((unsigned)f2bf(zv[3]) << 16);
    uint2 zp; zp.x = lo; zp.y = hi;
    *(uint2*)((char*)zls + swz256(rrow*256 + rc0*2)) = zp;
    if (c == 0){
      *(f32x4*)(out_mu + growr*STATE + rc0) = muv;
      *(f32x4*)(out_ls + growr*STATE + rc0) = lsv;
      if (t0 + tl == LSEQ-1)
        *(f32x4*)(out_zn + ((size_t)(brow0 + rrow))*STATE + rc0) = zv;
    }
    __syncthreads();                                   // (3) z visible, bls free

    #pragma unroll
    for (int nt=0; nt<2; nt++)
      #pragma unroll
      for (int r=0; r<4; r++){ pa0[nt][r] = pa1[nt][r]; pb0[nt][r] = pb1[nt][r]; }
  }

  // persist z state (role 0 writes)
  if (c == 0){
    unsigned short* zso = z_state + (size_t)brow0 * 128;
    for (int i = tid; i < 16*128; i += 512){
      int row = i >> 7, col = i & 127;
      zso[row*128 + col] = *(const unsigned short*)((const char*)zls + swz256(row*256 + col*2));
    }
  }
}

// ---------------- host launcher ----------------
extern "C" void kernel_launch(void* const* d_in, const int* in_sizes, int n_in,
                              void* d_out, int out_size, void* d_ws, size_t ws_size,
                              hipStream_t stream)
{
  const float* ext = (const float*)d_in[0];
  const float* obs = (const float*)d_in[1];
  const float* eps = (const float*)d_in[2];
  const float* Wu  = (const float*)d_in[3];
  const float* bu  = (const float*)d_in[4];
  const float* Wx  = (const float*)d_in[5];
  const float* bx  = (const float*)d_in[6];
  const float* W_ih= (const float*)d_in[7];
  const float* b_ih= (const float*)d_in[8];
  const float* W_hh= (const float*)d_in[9];
  const float* b_hh= (const float*)d_in[10];
  const float* Wa1 = (const float*)d_in[11];
  const float* ba1 = (const float*)d_in[12];
  const float* Wa2 = (const float*)d_in[13];
  const float* ba2 = (const float*)d_in[14];
  const float* pf1W= (const float*)d_in[15]; const float* pf1b = (const float*)d_in[16];
  const float* pf2W= (const float*)d_in[17]; const float* pf2b = (const float*)d_in[18];
  const float* pmuW= (const float*)d_in[19]; const float* pmub = (const float*)d_in[20];
  const float* plsW= (const float*)d_in[21]; const float* plsb = (const float*)d_in[22];
  const float* qf1W= (const float*)d_in[23]; const float* qf1b = (const float*)d_in[24];
  const float* qf2W= (const float*)d_in[25]; const float* qf2b = (const float*)d_in[26];
  const float* qmuW= (const float*)d_in[27]; const float* qmub = (const float*)d_in[28];

  int NC = 0;
  const int cands[7] = {1,2,4,8,16,32,64};
  size_t rows = 0;
  for (int ci=0; ci<7; ci++){
    size_t r = (size_t)(LSEQ/cands[ci])*BATCH;
    size_t elems = 3400000 + r*3072;
    if (elems * 2 <= ws_size){ NC = cands[ci]; rows = r; break; }
  }
  if (!NC) return;
  const int nsteps = LSEQ/NC;
  const int gx = (int)(rows/128);

  unsigned short* ws = (unsigned short*)d_ws;
  size_t off = 0;
  auto alloc = [&](size_t elems){
    unsigned short* p = ws + off;
    off += (elems + 127) & ~(size_t)127;
    return p;
  };

  unsigned short* Wu_t  = alloc(64*256);
  unsigned short* Wx_t  = alloc(64*256);
  unsigned short* Wih_t = alloc(256*256);
  unsigned short* Whh_t = alloc(256*256);
  unsigned short* Wa1_t = alloc(512*256);
  unsigned short* Wa2_t = alloc(256*256);
  unsigned short* fAp   = alloc(1024*256);     // [f1(512) | f2(512)] x [256 k]
  unsigned short* fAq   = alloc(1024*256);
  unsigned short* Wzz   = alloc(4*2*256*128);  // [role][mat][n][k]
  unsigned short* W2z   = alloc(4*2*128*256);  // [role][mat][n][k]
  unsigned short* d_state = alloc(256*256);
  unsigned short* z_state = alloc(256*128);
  unsigned short* mbx  = alloc(16*2*4*8192);   // tagged-line mailbox: 16g x 2par x 4roles x 16KB
  unsigned short* bufA  = alloc(rows*256);
  unsigned short* bufB  = alloc(rows*256);
  unsigned short* bufC  = alloc(rows*512);
  unsigned short* preP  = alloc(rows*1024);
  unsigned short* preQ  = alloc(rows*1024);
  if (off * sizeof(unsigned short) > ws_size) return;

  float* out_mu = (float*)d_out;
  float* out_ls = out_mu + (size_t)LSEQ*BATCH*STATE;
  float* out_dn = out_ls + (size_t)LSEQ*BATCH*STATE;
  float* out_zn = out_dn + (size_t)BATCH*KDIM;

  WDescs wd;
  int wi = 0;
  auto add = [&](const float* s, unsigned short* d, int Kk, int Nn, int ld, int ro, int co){
    wd.d[wi].src = s; wd.d[wi].dst = d; wd.d[wi].K = Kk; wd.d[wi].N = Nn;
    wd.d[wi].ld = ld; wd.d[wi].rowoff = ro; wd.d[wi].coloff = co; wi++;
  };
  add(Wu,   Wu_t,  64, 256, 256, 0, 0);
  add(Wx,   Wx_t,  64, 256, 256, 0, 0);
  add(W_ih, Wih_t, 256, 256, 256, 0, 0);
  add(W_hh, Whh_t, 256, 256, 256, 0, 0);
  add(Wa1,  Wa1_t, 512, 256, 256, 0, 0);
  add(Wa2,  Wa2_t, 256, 256, 256, 0, 0);
  add(pf1W, fAp,            256, 512, 512, 128, 0);
  add(pf2W, fAp + 512*256,  256, 512, 512, 128, 0);
  add(qf1W, fAq,            256, 512, 512, 128, 0);
  add(qf2W, fAq + 512*256,  256, 512, 512, 128, 0);
  for (int c=0; c<4; c++){
    const float* s1 = (c < 2) ? pf1W : qf1W;
    const float* s2 = (c < 2) ? pf2W : qf2W;
    add(s1, Wzz + (size_t)(c*2+0)*32768, 128, 256, 512, 0, (c&1)*256);
    add(s2, Wzz + (size_t)(c*2+1)*32768, 128, 256, 512, 0, (c&1)*256);
  }
  add(pmuW, W2z + (size_t)(0*2+0)*32768, 256, 128, 128, 0,   0);
  add(plsW, W2z + (size_t)(0*2+1)*32768, 256, 128, 128, 0,   0);
  add(pmuW, W2z + (size_t)(1*2+0)*32768, 256, 128, 128, 256, 0);
  add(plsW, W2z + (size_t)(1*2+1)*32768, 256, 128, 128, 256, 0);
  add(qmuW, W2z + (size_t)(2*2+0)*32768, 256, 128, 128, 0,   0);
  add(qmuW, W2z + (size_t)(3*2+0)*32768, 256, 128, 128, 256, 0);

  convert_weights<<<dim3(512,24), 256, 0, stream>>>(wd);

  for (int c=0; c<NC; ++c){
    const int t0 = c * nsteps;
    const size_t row0 = (size_t)t0 * BATCH;

    GArgs e{};
    e.g[0] = GArg{ext + row0*64, Wu_t, bu, bu, bufA, 64, 256, 0,   64, 1, 1};
    e.g[1] = GArg{obs + row0*64, Wx_t, bx, bx, bufC, 64, 512, 256, 64, 1, 1};
    gemm_multi<<<dim3(gx,2,2), 256, 0, stream>>>(e);

    GArgs rn{};
    rn.g[0] = GArg{bufA, Wih_t, b_ih, b_ih, bufB, 256, 256, 0, 256, 0, 0};
    gemm_multi<<<dim3(gx,2,1), 256, 0, stream>>>(rn);

    rnn_chunk<<<16, 256, 0, stream>>>(bufB, Whh_t, b_hh, bufC, out_dn, d_state, t0, nsteps);

    GArgs a1{};
    a1.g[0] = GArg{bufC, Wa1_t, ba1, ba1, bufA, 512, 256, 0, 512, 1, 0};
    gemm_multi<<<dim3(gx,2,1), 256, 0, stream>>>(a1);

    GArgs a2{};
    a2.g[0] = GArg{bufA, Wa2_t, ba2, ba2, bufB, 256, 256, 0, 256, 0, 0};
    gemm_multi<<<dim3(gx,2,1), 256, 0, stream>>>(a2);

    GArgs pr{};
    pr.g[0] = GArg{bufB, fAp, pf1b, pf2b, preP, 256, 1024, 0, 256, 0, 0};
    pr.g[1] = GArg{bufC, fAq, qf1b, qf2b, preQ, 512, 1024, 0, 256, 0, 0};
    gemm_multi<<<dim3(gx,8,2), 256, 0, stream>>>(pr);

    zrec_mb<<<64, 512, 0, stream>>>(preP, preQ, Wzz, W2z,
                                    pmub, plsb, qmub, eps, out_mu, out_ls, out_zn,
                                    z_state, mbx, t0, nsteps, c*nsteps);
  }
}